// Round 7
// baseline (4473.384 us; speedup 1.0000x reference)
//
#include <hip/hip_runtime.h>
#include <stdint.h>
#include <stddef.h>

// LSTM: B=64, T=512, I=H=1024. fp32 in/out, bf16 MFMA compute internally.
//
//   k_lstm v6: v5 structure with the split-asm load hazard FIXED.
//   - EPOCH-IN-VALUE sync (bit14 parity in every bf16; |h|<1 so bit14 free).
//   - Wave pair kq polls+stages ONLY h-quarter kq; pair-sync via LDS counter.
//   - Producer: direct per-thread u32 sc1 h-store right after gate math.
//   - POLL IS ONE FUSED ASM BLOCK: 16x global_load_dwordx4 sc1 + s_waitcnt
//     vmcnt(0) in a single asm with "=&v" outputs. Previous versions issued
//     loads in separate asm blocks and waited later -- the compiler believes
//     an asm output is defined at block end, so it may copy/spill a register
//     whose load is still in flight (allocation-luck bug; v4b's NaN).
//   - Bounded spins (poll 65536 rounds, pair 2^22): any protocol stall ->
//     diagnosable wrong answer instead of a wedged container.

typedef unsigned short u16;
typedef unsigned int u32;
typedef short bf16x8 __attribute__((ext_vector_type(8)));
typedef float f32x4 __attribute__((ext_vector_type(4)));
typedef u32 u32x4 __attribute__((ext_vector_type(4)));

#define B_ 64
#define T_ 512
#define I_ 1024
#define H_ 1024
#define NWG 64
#define BTH (B_ * T_ * H_)

// ws layout (bytes)
#define OFF_XB 0UL                 // 64 MB  : x bf16 [64][512][1024]
#define OFF_WT 67108864UL          // 8 MB   : Wcat bf16, reordered [4096][1024]
#define OFF_UT 75497472UL          // 8 MB   : Ucat bf16, reordered [4096][1024]
#define OFF_XG 83886080UL          // 256 MB : xg bf16 [512][64][64][64]
#define OFF_HB 352321536UL         // 256 KB : h dbuf, granule layout 2x[128][64][8]
#define OFF_FLG 352583680UL        // flags u32[64] (unused by k_lstm)

#define EPOCH_MASK 0x40004000u
#define EPOCH_CLR  0xBFFFBFFFu

// LDS map (k_lstm)
#define LDS_QC 131072   // u32[4] quarter counters
#define LDS_SZ 131088

__device__ __forceinline__ u16 f2bf(float f) {
  u32 u = __builtin_bit_cast(u32, f);
  return (u16)((u + 0x7FFFu + ((u >> 16) & 1u)) >> 16);
}
__device__ __forceinline__ float bf2f(u16 h) {
  u32 u = ((u32)h) << 16;
  return __builtin_bit_cast(float, u);
}
__device__ __forceinline__ float sigm(float x) { return 1.f / (1.f + __expf(-x)); }
__device__ __forceinline__ float tanh_(float x) {
  float e = __expf(-2.f * fabsf(x));
  float t = (1.f - e) / (1.f + e);
  return x >= 0.f ? t : -t;
}
__device__ __forceinline__ void async16(const void* g, void* l) {
  __builtin_amdgcn_global_load_lds((const __attribute__((address_space(1))) void*)g,
                                   (__attribute__((address_space(3))) void*)l, 16, 0, 0);
}
__device__ __forceinline__ void st_u32_sc1(u32* p, u32 v) {
  asm volatile("global_store_dword %0, %1, off sc1" : : "v"(p), "v"(v) : "memory");
}

// Fused poll round: load 16 rows (4 bases x 4 signed imm offsets, stride
// 2048 B) device-coherent, wait inside the SAME asm block. Outputs are fully
// defined at block end -- no in-flight-load window for the allocator to break.
__device__ __forceinline__ void poll16(const u16* b0, const u16* b1,
                                       const u16* b2, const u16* b3,
                                       u32x4 v[16]) {
  asm volatile(
      "global_load_dwordx4 %0, %16, off offset:-4096 sc1\n\t"
      "global_load_dwordx4 %1, %16, off offset:-2048 sc1\n\t"
      "global_load_dwordx4 %2, %16, off sc1\n\t"
      "global_load_dwordx4 %3, %16, off offset:2048 sc1\n\t"
      "global_load_dwordx4 %4, %17, off offset:-4096 sc1\n\t"
      "global_load_dwordx4 %5, %17, off offset:-2048 sc1\n\t"
      "global_load_dwordx4 %6, %17, off sc1\n\t"
      "global_load_dwordx4 %7, %17, off offset:2048 sc1\n\t"
      "global_load_dwordx4 %8, %18, off offset:-4096 sc1\n\t"
      "global_load_dwordx4 %9, %18, off offset:-2048 sc1\n\t"
      "global_load_dwordx4 %10, %18, off sc1\n\t"
      "global_load_dwordx4 %11, %18, off offset:2048 sc1\n\t"
      "global_load_dwordx4 %12, %19, off offset:-4096 sc1\n\t"
      "global_load_dwordx4 %13, %19, off offset:-2048 sc1\n\t"
      "global_load_dwordx4 %14, %19, off sc1\n\t"
      "global_load_dwordx4 %15, %19, off offset:2048 sc1\n\t"
      "s_waitcnt vmcnt(0)"
      : "=&v"(v[0]), "=&v"(v[1]), "=&v"(v[2]), "=&v"(v[3]),
        "=&v"(v[4]), "=&v"(v[5]), "=&v"(v[6]), "=&v"(v[7]),
        "=&v"(v[8]), "=&v"(v[9]), "=&v"(v[10]), "=&v"(v[11]),
        "=&v"(v[12]), "=&v"(v[13]), "=&v"(v[14]), "=&v"(v[15])
      : "v"(b0), "v"(b1), "v"(b2), "v"(b3)
      : "memory");
}

// ---------------------------------------------------------------- init
__global__ void k_init(u16* hbuf, u32* flg) {
  int i = blockIdx.x * 256 + threadIdx.x;  // 64 blocks -> 16384 threads
  uint4 z;
  if (i < 8192) {               // buf0 = h_0 = zeros, epoch 0
    z.x = 0u; z.y = 0u; z.z = 0u; z.w = 0u;
  } else {                      // buf1 = poison with bit14=1 (!= h_1's epoch 0)
    z.x = EPOCH_MASK; z.y = EPOCH_MASK; z.z = EPOCH_MASK; z.w = EPOCH_MASK;
  }
  ((uint4*)hbuf)[i] = z;
  if (i < NWG) flg[i] = 0u;
}

// ---------------------------------------------------------------- x -> bf16
__global__ void k_cvt_x(const float4* __restrict__ x, ushort4* __restrict__ xb) {
  size_t i = (size_t)blockIdx.x * 256 + threadIdx.x;  // 8388608 float4s
  float4 v = x[i];
  ushort4 o;
  o.x = f2bf(v.x); o.y = f2bf(v.y); o.z = f2bf(v.z); o.w = f2bf(v.w);
  xb[i] = o;
}

// ---------------------------------------------------------------- W/U -> bf16, reordered
__global__ void k_cvt_w(const float* __restrict__ Wi, const float* __restrict__ Wf,
                        const float* __restrict__ Wo, const float* __restrict__ Wg,
                        const float* __restrict__ Ui, const float* __restrict__ Uf,
                        const float* __restrict__ Uo, const float* __restrict__ Ug,
                        u16* __restrict__ Wt, u16* __restrict__ Ut) {
  int idx = blockIdx.x * 256 + threadIdx.x;  // 4096 rows * 128 segs
  int r = idx >> 7;
  int s = idx & 127;
  int w = r >> 6, c = r & 63, g = c >> 4, jl = c & 15;
  int hrow = w * 16 + jl;
  const float* Wsrc = (g == 0) ? Wi : (g == 1) ? Wf : (g == 2) ? Wo : Wg;
  const float* Usrc = (g == 0) ? Ui : (g == 1) ? Uf : (g == 2) ? Uo : Ug;
  int so = hrow * 1024 + s * 8;
  int dovr = r * 1024 + s * 8;
  ushort4 a, b;
  a.x = f2bf(Wsrc[so + 0]); a.y = f2bf(Wsrc[so + 1]); a.z = f2bf(Wsrc[so + 2]); a.w = f2bf(Wsrc[so + 3]);
  b.x = f2bf(Wsrc[so + 4]); b.y = f2bf(Wsrc[so + 5]); b.z = f2bf(Wsrc[so + 6]); b.w = f2bf(Wsrc[so + 7]);
  *(ushort4*)&Wt[dovr] = a;
  *(ushort4*)&Wt[dovr + 4] = b;
  a.x = f2bf(Usrc[so + 0]); a.y = f2bf(Usrc[so + 1]); a.z = f2bf(Usrc[so + 2]); a.w = f2bf(Usrc[so + 3]);
  b.x = f2bf(Usrc[so + 4]); b.y = f2bf(Usrc[so + 5]); b.z = f2bf(Usrc[so + 6]); b.w = f2bf(Usrc[so + 7]);
  *(ushort4*)&Ut[dovr] = a;
  *(ushort4*)&Ut[dovr + 4] = b;
}

// ---------------------------------------------------------------- input GEMM
__global__ __launch_bounds__(256) void k_gemm(const u16* __restrict__ xb,
                                              const u16* __restrict__ Wt,
                                              u16* __restrict__ xg) {
  __shared__ u16 As[4 * 128 * 8];
  __shared__ u16 Bs[4 * 128 * 8];
  const int tid = threadIdx.x;
  const int lane = tid & 63, wave = tid >> 6;
  const int wm = wave >> 1, wn = wave & 1;
  const int lr = lane & 15, lq = lane >> 4;
  const int m0 = blockIdx.y * 128, n0 = blockIdx.x * 128;

  f32x4 acc[4][4];
#pragma unroll
  for (int mt = 0; mt < 4; ++mt)
#pragma unroll
    for (int nt = 0; nt < 4; ++nt) acc[mt][nt] = {0.f, 0.f, 0.f, 0.f};

  for (int kk = 0; kk < 32; ++kk) {
    int k0 = kk * 32;
    __syncthreads();
#pragma unroll
    for (int uu = 0; uu < 2; ++uu) {
      int u = wave * 2 + uu;
      int kq = u >> 1, rh = u & 1;
      int row = rh * 64 + lane;
      async16(&xb[(size_t)(m0 + row) * 1024 + k0 + kq * 8], &As[kq * 1024 + rh * 512]);
      async16(&Wt[(size_t)(n0 + row) * 1024 + k0 + kq * 8], &Bs[kq * 1024 + rh * 512]);
    }
    __syncthreads();

    bf16x8 af[4], bfr[4];
#pragma unroll
    for (int mt = 0; mt < 4; ++mt)
      af[mt] = *(const bf16x8*)&As[lq * 1024 + (wm * 64 + mt * 16 + lr) * 8];
#pragma unroll
    for (int nt = 0; nt < 4; ++nt)
      bfr[nt] = *(const bf16x8*)&Bs[lq * 1024 + (wn * 64 + nt * 16 + lr) * 8];
#pragma unroll
    for (int mt = 0; mt < 4; ++mt)
#pragma unroll
      for (int nt = 0; nt < 4; ++nt)
        acc[mt][nt] = __builtin_amdgcn_mfma_f32_16x16x32_bf16(af[mt], bfr[nt], acc[mt][nt], 0, 0, 0);
  }

#pragma unroll
  for (int mt = 0; mt < 4; ++mt)
#pragma unroll
    for (int nt = 0; nt < 4; ++nt)
#pragma unroll
      for (int r = 0; r < 4; ++r) {
        int mg = m0 + wm * 64 + mt * 16 + lq * 4 + r;
        int ngl = n0 + wn * 64 + nt * 16 + lr;
        int b = mg >> 9, t = mg & 511;
        int w = ngl >> 6, c = ngl & 63;
        xg[(size_t)t * 262144 + w * 4096 + b * 64 + c] = f2bf(acc[mt][nt][r]);
      }
}

// ---------------------------------------------------------------- recurrence
// 64 WGs x 512 threads (8 waves = 4 kq x 2 ng). WG w owns gate cols
// [64w, 64w+64) => h cols [16w, 16w+16). Pair kq stages h-quarter kq only.
__global__ __launch_bounds__(512, 2) void k_lstm(
    const u16* __restrict__ Ut, const u16* __restrict__ xg, u16* hbuf,
    const float* __restrict__ bi, const float* __restrict__ bf_,
    const float* __restrict__ bo, const float* __restrict__ bg,
    float* __restrict__ out) {
  __shared__ __align__(16) unsigned char LDSB[LDS_SZ];
  u16* hL = (u16*)LDSB;                 // h staged: [granule 128][b 64][8 u16]
  float* P = (float*)LDSB;              // aliased after B2: [ng 2][kq 4][b 64][34]
  u32* qc = (u32*)(LDSB + LDS_QC);      // quarter ready counters (monotone)

  const int tid = threadIdx.x;
  const int lane = tid & 63, wave = tid >> 6;
  const int lr = lane & 15, lq = lane >> 4;
  const int kq = wave >> 1, ng = wave & 1;
  const int pairtid = ng * 64 + lane;   // 0..127 within pair kq
  const int w = blockIdx.x;

  if (tid < 4) qc[tid] = 0u;

  // U fragments resident in VGPRs for all 512 steps.
  bf16x8 Bf[2][8];
#pragma unroll
  for (int nt = 0; nt < 2; ++nt)
#pragma unroll
    for (int ks = 0; ks < 8; ++ks) {
      int n = w * 64 + ng * 32 + nt * 16 + lr;
      int k = kq * 256 + ks * 32 + lq * 8;
      Bf[nt][ks] = *(const bf16x8*)&Ut[(size_t)n * 1024 + k];
    }

  // elementwise ownership: batch b = lane, q = wave -> jl = 2q, 2q+1
  const int q = wave, b = lane;
  float bia[2][4];
#pragma unroll
  for (int p = 0; p < 2; ++p) {
    int hc = w * 16 + q * 2 + p;
    bia[p][0] = bi[hc]; bia[p][1] = bf_[hc]; bia[p][2] = bo[hc]; bia[p][3] = bg[hc];
  }
  float cst0 = 0.f, cst1 = 0.f;
  const int Gh = w * 2 + (q >> 2);     // output granule
  const int c8 = (q * 2) & 7;          // position within granule

  __syncthreads();  // qc init visible

  for (int t = 0; t < T_; ++t) {
    const u16* hin = hbuf + (size_t)(t & 1) * 65536;
    const int ep = (t >> 1) & 1;        // expected epoch parity of h_t

    // xg slice loads (latency hides under the h poll)
    const u16* xgp = xg + (size_t)t * 262144 + w * 4096;
    u32 xv[4];
#pragma unroll
    for (int g = 0; g < 4; ++g)
      xv[g] = *(const u32*)&xgp[b * 64 + g * 16 + q * 2];

    // ---- poll-stage OWN quarter kq (32 KB) into LDS; bit14 is the flag ----
    // pair thread handles rows R = kq*2048 + pairtid + 128*i, i=0..15
    // (row stride 2048 B; 4 bases x {-4096,-2048,0,+2048} imm offsets)
    {
      const u16* A = hin + (size_t)(kq * 2048 + pairtid) * 8;
      const u16* b0 = A + 2 * 1024;
      const u16* b1 = A + 6 * 1024;
      const u16* b2 = A + 10 * 1024;
      const u16* b3 = A + 14 * 1024;
      u32x4 v[16];
      u32 pend = 0xFFFFu;
      u32 spin = 0;
      do {
        if (spin > 1) __builtin_amdgcn_s_sleep(1);  // backoff after 2 fast rounds
        if (++spin > 65536u) break;                 // unreachable; anti-wedge only
        poll16(b0, b1, b2, b3, v);                  // fused: loads + vmcnt(0)
        __builtin_amdgcn_sched_barrier(0);
        if (ep) {
#pragma unroll
          for (int i = 0; i < 16; ++i)
            if (pend & (1u << i)) {
              u32 aa = v[i][0] & v[i][1] & v[i][2] & v[i][3];
              if ((aa & EPOCH_MASK) == EPOCH_MASK) {
                u32x4 wv;
                wv[0] = v[i][0] & EPOCH_CLR; wv[1] = v[i][1] & EPOCH_CLR;
                wv[2] = v[i][2] & EPOCH_CLR; wv[3] = v[i][3] & EPOCH_CLR;
                *(u32x4*)&hL[(size_t)(kq * 2048 + pairtid + (i << 7)) * 8] = wv;
                pend &= ~(1u << i);
              }
            }
        } else {
#pragma unroll
          for (int i = 0; i < 16; ++i)
            if (pend & (1u << i)) {
              u32 oo = v[i][0] | v[i][1] | v[i][2] | v[i][3];
              if ((oo & EPOCH_MASK) == 0u) {
                *(u32x4*)&hL[(size_t)(kq * 2048 + pairtid + (i << 7)) * 8] = v[i];
                pend &= ~(1u << i);
              }
            }
        }
      } while (pend);
    }
    // signal quarter share done; wait for partner wave (pair barrier)
    asm volatile("s_waitcnt lgkmcnt(0)" ::: "memory");
    if (lane == 0) atomicAdd(&qc[kq], 1u);
    {
      volatile u32* qp = (volatile u32*)&qc[kq];
      u32 tgt = 2u * (u32)(t + 1);
      u32 guard = 0;
      while (*qp < tgt) { if (++guard > (1u << 22)) break; }  // anti-wedge only
    }
    __builtin_amdgcn_sched_barrier(0);
    asm volatile("" ::: "memory");

    // ---- MFMA on own quarter (starts as soon as THIS quarter is staged) ----
    f32x4 acc[4][2];
#pragma unroll
    for (int mt = 0; mt < 4; ++mt) { acc[mt][0] = {0.f,0.f,0.f,0.f}; acc[mt][1] = {0.f,0.f,0.f,0.f}; }

#pragma unroll
    for (int ks = 0; ks < 8; ++ks) {
      int Gk = kq * 32 + ks * 4 + lq;
      bf16x8 af[4];
#pragma unroll
      for (int mt = 0; mt < 4; ++mt)
        af[mt] = *(const bf16x8*)&hL[(Gk * 64 + mt * 16 + lr) * 8];
#pragma unroll
      for (int mt = 0; mt < 4; ++mt) {
        acc[mt][0] = __builtin_amdgcn_mfma_f32_16x16x32_bf16(af[mt], Bf[0][ks], acc[mt][0], 0, 0, 0);
        acc[mt][1] = __builtin_amdgcn_mfma_f32_16x16x32_bf16(af[mt], Bf[1][ks], acc[mt][1], 0, 0, 0);
      }
    }
    __syncthreads();  // B2: all hL reads done -> safe to alias P

    // K-split partials -> LDS (stride 34: write 2-way, read 2-way => free)
#pragma unroll
    for (int mt = 0; mt < 4; ++mt)
#pragma unroll
      for (int nt = 0; nt < 2; ++nt)
#pragma unroll
        for (int r = 0; r < 4; ++r) {
          int m = mt * 16 + lq * 4 + r;
          int cc = nt * 16 + lr;
          P[((ng * 4 + kq) * 64 + m) * 34 + cc] = acc[mt][nt][r];
        }
    __syncthreads();  // B3: P complete

    float hv[2];
#pragma unroll
    for (int p = 0; p < 2; ++p) {
      int jl = q * 2 + p;
      float pre[4];
#pragma unroll
      for (int g = 0; g < 4; ++g) {
        int cc = (g & 1) * 16 + jl;
        int base = (g >> 1) * 4 * 64;
        float s = P[(base + 0 * 64 + b) * 34 + cc] + P[(base + 1 * 64 + b) * 34 + cc] +
                  P[(base + 2 * 64 + b) * 34 + cc] + P[(base + 3 * 64 + b) * 34 + cc];
        u16 xh = (u16)(p == 0 ? (xv[g] & 0xFFFFu) : (xv[g] >> 16));
        pre[g] = s + bf2f(xh) + bia[p][g];
      }
      float iv = sigm(pre[0]);
      float fv = sigm(pre[1]);
      float ov = sigm(pre[2]);
      float gv = tanh_(pre[3]);
      float cn = fv * (p == 0 ? cst0 : cst1) + iv * gv;
      if (p == 0) cst0 = cn; else cst1 = cn;
      hv[p] = ov * tanh_(cn);
    }

    float2 f2v; f2v.x = hv[0]; f2v.y = hv[1];

    if (t < T_ - 1) {
      // h broadcast FIRST (critical path): direct per-thread u32, sc1.
      u16* hout = hbuf + (size_t)((t + 1) & 1) * 65536;
      u32 hpack = (u32)f2bf(hv[0]) | ((u32)f2bf(hv[1]) << 16);
      if (((t + 1) >> 1) & 1) hpack |= EPOCH_MASK;
      st_u32_sc1((u32*)&hout[(size_t)(Gh * 64 + b) * 8 + c8], hpack);
      // out store (off critical path)
      *(float2*)&out[((size_t)b * 512 + t) * 1024 + w * 16 + q * 2] = f2v;
    } else {
      *(float2*)&out[((size_t)b * 512 + t) * 1024 + w * 16 + q * 2] = f2v;
      *(float2*)&out[(size_t)BTH + b * 1024 + w * 16 + q * 2] = f2v;          // h_last
      float2 c2v; c2v.x = cst0; c2v.y = cst1;
      *(float2*)&out[(size_t)BTH + B_ * H_ + b * 1024 + w * 16 + q * 2] = c2v; // c_last
    }

    __syncthreads();  // B4: P reads done before next step's poll ds_writes
  }
}

// ---------------------------------------------------------------- launch
extern "C" void kernel_launch(void* const* d_in, const int* in_sizes, int n_in,
                              void* d_out, int out_size, void* d_ws, size_t ws_size,
                              hipStream_t stream) {
  const float* x  = (const float*)d_in[0];
  const float* Wi = (const float*)d_in[1];
  const float* Wf = (const float*)d_in[2];
  const float* Wo = (const float*)d_in[3];
  const float* Wg = (const float*)d_in[4];
  const float* Ui = (const float*)d_in[5];
  const float* Uf = (const float*)d_in[6];
  const float* Uo = (const float*)d_in[7];
  const float* Ug = (const float*)d_in[8];
  const float* bi = (const float*)d_in[9];
  const float* bf = (const float*)d_in[10];
  const float* bo = (const float*)d_in[11];
  const float* bg = (const float*)d_in[12];
  float* out = (float*)d_out;

  char* ws = (char*)d_ws;
  u16* xb   = (u16*)(ws + OFF_XB);
  u16* Wt   = (u16*)(ws + OFF_WT);
  u16* Ut   = (u16*)(ws + OFF_UT);
  u16* xg   = (u16*)(ws + OFF_XG);
  u16* hbuf = (u16*)(ws + OFF_HB);
  u32* flg  = (u32*)(ws + OFF_FLG);

  k_init<<<64, 256, 0, stream>>>(hbuf, flg);
  k_cvt_x<<<32768, 256, 0, stream>>>((const float4*)x, (ushort4*)xb);
  k_cvt_w<<<2048, 256, 0, stream>>>(Wi, Wf, Wo, Wg, Ui, Uf, Uo, Ug, Wt, Ut);
  k_gemm<<<dim3(32, 256), 256, 0, stream>>>(xb, Wt, xg);
  k_lstm<<<NWG, 512, 0, stream>>>(Ut, xg, hbuf, bi, bf, bo, bg, out);
}

// Round 8
// 3886.179 us; speedup vs baseline: 1.1511x; 1.1511x over previous
//
#include <hip/hip_runtime.h>
#include <stdint.h>
#include <stddef.h>

// LSTM: B=64, T=512, I=H=1024. fp32 in/out, bf16 MFMA compute internally.
//
//   k_lstm v7 = v6 (fused-poll, quarter pipeline) + v3's gathered producer
//   tail (atomic 16B-row h stores), with the gather transposed to kill v3's
//   16-way LDS bank conflict.
//   - EPOCH-IN-VALUE sync (bit14 parity in every bf16; |h|<1 so bit14 free).
//   - Wave pair kq polls+stages ONLY h-quarter kq; pair-sync via LDS counter.
//   - Poll is ONE fused asm block (16x global_load_dwordx4 sc1 + vmcnt(0),
//     "=&v" outputs): no in-flight-load window for the allocator (v6 fix).
//   - Producer: EW writes hXt[q*64+b] (conflict-free), B4, then waves 0/2
//     assemble whole 16B rows and store with dwordx4 sc1 -> rows become
//     visible ATOMICALLY (v6's per-u32 stores caused partial-row poll
//     retries: FETCH 398->424 GB, +1us/step).
//   - Bounded spins: any protocol stall -> diagnosable failure, not a wedge.

typedef unsigned short u16;
typedef unsigned int u32;
typedef short bf16x8 __attribute__((ext_vector_type(8)));
typedef float f32x4 __attribute__((ext_vector_type(4)));
typedef u32 u32x4 __attribute__((ext_vector_type(4)));

#define B_ 64
#define T_ 512
#define I_ 1024
#define H_ 1024
#define NWG 64
#define BTH (B_ * T_ * H_)

// ws layout (bytes)
#define OFF_XB 0UL                 // 64 MB  : x bf16 [64][512][1024]
#define OFF_WT 67108864UL          // 8 MB   : Wcat bf16, reordered [4096][1024]
#define OFF_UT 75497472UL          // 8 MB   : Ucat bf16, reordered [4096][1024]
#define OFF_XG 83886080UL          // 256 MB : xg bf16 [512][64][64][64]
#define OFF_HB 352321536UL         // 256 KB : h dbuf, granule layout 2x[128][64][8]
#define OFF_FLG 352583680UL        // flags u32[64] (unused by k_lstm)

#define EPOCH_MASK 0x40004000u
#define EPOCH_CLR  0xBFFFBFFFu

// LDS map (k_lstm)
#define LDS_HX 131072   // u32 hXt[8][64] transposed gather (2 KB)
#define LDS_QC 133120   // u32[4] quarter counters
#define LDS_SZ 133136

__device__ __forceinline__ u16 f2bf(float f) {
  u32 u = __builtin_bit_cast(u32, f);
  return (u16)((u + 0x7FFFu + ((u >> 16) & 1u)) >> 16);
}
__device__ __forceinline__ float bf2f(u16 h) {
  u32 u = ((u32)h) << 16;
  return __builtin_bit_cast(float, u);
}
__device__ __forceinline__ float sigm(float x) { return 1.f / (1.f + __expf(-x)); }
__device__ __forceinline__ float tanh_(float x) {
  float e = __expf(-2.f * fabsf(x));
  float t = (1.f - e) / (1.f + e);
  return x >= 0.f ? t : -t;
}
__device__ __forceinline__ void async16(const void* g, void* l) {
  __builtin_amdgcn_global_load_lds((const __attribute__((address_space(1))) void*)g,
                                   (__attribute__((address_space(3))) void*)l, 16, 0, 0);
}
__device__ __forceinline__ void st16_sc1(u16* p, u32x4 v) {
  asm volatile("global_store_dwordx4 %0, %1, off sc1" : : "v"(p), "v"(v) : "memory");
}

// Fused poll round: load 16 rows (4 bases x 4 signed imm offsets, stride
// 2048 B) device-coherent, wait inside the SAME asm block. Outputs are fully
// defined at block end -- no in-flight-load window for the allocator to break.
__device__ __forceinline__ void poll16(const u16* b0, const u16* b1,
                                       const u16* b2, const u16* b3,
                                       u32x4 v[16]) {
  asm volatile(
      "global_load_dwordx4 %0, %16, off offset:-4096 sc1\n\t"
      "global_load_dwordx4 %1, %16, off offset:-2048 sc1\n\t"
      "global_load_dwordx4 %2, %16, off sc1\n\t"
      "global_load_dwordx4 %3, %16, off offset:2048 sc1\n\t"
      "global_load_dwordx4 %4, %17, off offset:-4096 sc1\n\t"
      "global_load_dwordx4 %5, %17, off offset:-2048 sc1\n\t"
      "global_load_dwordx4 %6, %17, off sc1\n\t"
      "global_load_dwordx4 %7, %17, off offset:2048 sc1\n\t"
      "global_load_dwordx4 %8, %18, off offset:-4096 sc1\n\t"
      "global_load_dwordx4 %9, %18, off offset:-2048 sc1\n\t"
      "global_load_dwordx4 %10, %18, off sc1\n\t"
      "global_load_dwordx4 %11, %18, off offset:2048 sc1\n\t"
      "global_load_dwordx4 %12, %19, off offset:-4096 sc1\n\t"
      "global_load_dwordx4 %13, %19, off offset:-2048 sc1\n\t"
      "global_load_dwordx4 %14, %19, off sc1\n\t"
      "global_load_dwordx4 %15, %19, off offset:2048 sc1\n\t"
      "s_waitcnt vmcnt(0)"
      : "=&v"(v[0]), "=&v"(v[1]), "=&v"(v[2]), "=&v"(v[3]),
        "=&v"(v[4]), "=&v"(v[5]), "=&v"(v[6]), "=&v"(v[7]),
        "=&v"(v[8]), "=&v"(v[9]), "=&v"(v[10]), "=&v"(v[11]),
        "=&v"(v[12]), "=&v"(v[13]), "=&v"(v[14]), "=&v"(v[15])
      : "v"(b0), "v"(b1), "v"(b2), "v"(b3)
      : "memory");
}

// ---------------------------------------------------------------- init
__global__ void k_init(u16* hbuf, u32* flg) {
  int i = blockIdx.x * 256 + threadIdx.x;  // 64 blocks -> 16384 threads
  uint4 z;
  if (i < 8192) {               // buf0 = h_0 = zeros, epoch 0
    z.x = 0u; z.y = 0u; z.z = 0u; z.w = 0u;
  } else {                      // buf1 = poison with bit14=1 (!= h_1's epoch 0)
    z.x = EPOCH_MASK; z.y = EPOCH_MASK; z.z = EPOCH_MASK; z.w = EPOCH_MASK;
  }
  ((uint4*)hbuf)[i] = z;
  if (i < NWG) flg[i] = 0u;
}

// ---------------------------------------------------------------- x -> bf16
__global__ void k_cvt_x(const float4* __restrict__ x, ushort4* __restrict__ xb) {
  size_t i = (size_t)blockIdx.x * 256 + threadIdx.x;  // 8388608 float4s
  float4 v = x[i];
  ushort4 o;
  o.x = f2bf(v.x); o.y = f2bf(v.y); o.z = f2bf(v.z); o.w = f2bf(v.w);
  xb[i] = o;
}

// ---------------------------------------------------------------- W/U -> bf16, reordered
__global__ void k_cvt_w(const float* __restrict__ Wi, const float* __restrict__ Wf,
                        const float* __restrict__ Wo, const float* __restrict__ Wg,
                        const float* __restrict__ Ui, const float* __restrict__ Uf,
                        const float* __restrict__ Uo, const float* __restrict__ Ug,
                        u16* __restrict__ Wt, u16* __restrict__ Ut) {
  int idx = blockIdx.x * 256 + threadIdx.x;  // 4096 rows * 128 segs
  int r = idx >> 7;
  int s = idx & 127;
  int w = r >> 6, c = r & 63, g = c >> 4, jl = c & 15;
  int hrow = w * 16 + jl;
  const float* Wsrc = (g == 0) ? Wi : (g == 1) ? Wf : (g == 2) ? Wo : Wg;
  const float* Usrc = (g == 0) ? Ui : (g == 1) ? Uf : (g == 2) ? Uo : Ug;
  int so = hrow * 1024 + s * 8;
  int dovr = r * 1024 + s * 8;
  ushort4 a, b;
  a.x = f2bf(Wsrc[so + 0]); a.y = f2bf(Wsrc[so + 1]); a.z = f2bf(Wsrc[so + 2]); a.w = f2bf(Wsrc[so + 3]);
  b.x = f2bf(Wsrc[so + 4]); b.y = f2bf(Wsrc[so + 5]); b.z = f2bf(Wsrc[so + 6]); b.w = f2bf(Wsrc[so + 7]);
  *(ushort4*)&Wt[dovr] = a;
  *(ushort4*)&Wt[dovr + 4] = b;
  a.x = f2bf(Usrc[so + 0]); a.y = f2bf(Usrc[so + 1]); a.z = f2bf(Usrc[so + 2]); a.w = f2bf(Usrc[so + 3]);
  b.x = f2bf(Usrc[so + 4]); b.y = f2bf(Usrc[so + 5]); b.z = f2bf(Usrc[so + 6]); b.w = f2bf(Usrc[so + 7]);
  *(ushort4*)&Ut[dovr] = a;
  *(ushort4*)&Ut[dovr + 4] = b;
}

// ---------------------------------------------------------------- input GEMM
__global__ __launch_bounds__(256) void k_gemm(const u16* __restrict__ xb,
                                              const u16* __restrict__ Wt,
                                              u16* __restrict__ xg) {
  __shared__ u16 As[4 * 128 * 8];
  __shared__ u16 Bs[4 * 128 * 8];
  const int tid = threadIdx.x;
  const int lane = tid & 63, wave = tid >> 6;
  const int wm = wave >> 1, wn = wave & 1;
  const int lr = lane & 15, lq = lane >> 4;
  const int m0 = blockIdx.y * 128, n0 = blockIdx.x * 128;

  f32x4 acc[4][4];
#pragma unroll
  for (int mt = 0; mt < 4; ++mt)
#pragma unroll
    for (int nt = 0; nt < 4; ++nt) acc[mt][nt] = {0.f, 0.f, 0.f, 0.f};

  for (int kk = 0; kk < 32; ++kk) {
    int k0 = kk * 32;
    __syncthreads();
#pragma unroll
    for (int uu = 0; uu < 2; ++uu) {
      int u = wave * 2 + uu;
      int kq = u >> 1, rh = u & 1;
      int row = rh * 64 + lane;
      async16(&xb[(size_t)(m0 + row) * 1024 + k0 + kq * 8], &As[kq * 1024 + rh * 512]);
      async16(&Wt[(size_t)(n0 + row) * 1024 + k0 + kq * 8], &Bs[kq * 1024 + rh * 512]);
    }
    __syncthreads();

    bf16x8 af[4], bfr[4];
#pragma unroll
    for (int mt = 0; mt < 4; ++mt)
      af[mt] = *(const bf16x8*)&As[lq * 1024 + (wm * 64 + mt * 16 + lr) * 8];
#pragma unroll
    for (int nt = 0; nt < 4; ++nt)
      bfr[nt] = *(const bf16x8*)&Bs[lq * 1024 + (wn * 64 + nt * 16 + lr) * 8];
#pragma unroll
    for (int mt = 0; mt < 4; ++mt)
#pragma unroll
      for (int nt = 0; nt < 4; ++nt)
        acc[mt][nt] = __builtin_amdgcn_mfma_f32_16x16x32_bf16(af[mt], bfr[nt], acc[mt][nt], 0, 0, 0);
  }

#pragma unroll
  for (int mt = 0; mt < 4; ++mt)
#pragma unroll
    for (int nt = 0; nt < 4; ++nt)
#pragma unroll
      for (int r = 0; r < 4; ++r) {
        int mg = m0 + wm * 64 + mt * 16 + lq * 4 + r;
        int ngl = n0 + wn * 64 + nt * 16 + lr;
        int b = mg >> 9, t = mg & 511;
        int w = ngl >> 6, c = ngl & 63;
        xg[(size_t)t * 262144 + w * 4096 + b * 64 + c] = f2bf(acc[mt][nt][r]);
      }
}

// ---------------------------------------------------------------- recurrence
// 64 WGs x 512 threads (8 waves = 4 kq x 2 ng). WG w owns gate cols
// [64w, 64w+64) => h cols [16w, 16w+16). Pair kq stages h-quarter kq only.
__global__ __launch_bounds__(512, 2) void k_lstm(
    const u16* __restrict__ Ut, const u16* __restrict__ xg, u16* hbuf,
    const float* __restrict__ bi, const float* __restrict__ bf_,
    const float* __restrict__ bo, const float* __restrict__ bg,
    float* __restrict__ out) {
  __shared__ __align__(16) unsigned char LDSB[LDS_SZ];
  u16* hL = (u16*)LDSB;                 // h staged: [granule 128][b 64][8 u16]
  float* P = (float*)LDSB;              // aliased after B2: [ng 2][kq 4][b 64][34]
  u32* hXt = (u32*)(LDSB + LDS_HX);     // transposed gather [q 8][b 64]
  u32* qc = (u32*)(LDSB + LDS_QC);      // quarter ready counters (monotone)

  const int tid = threadIdx.x;
  const int lane = tid & 63, wave = tid >> 6;
  const int lr = lane & 15, lq = lane >> 4;
  const int kq = wave >> 1, ng = wave & 1;
  const int pairtid = ng * 64 + lane;   // 0..127 within pair kq
  const int w = blockIdx.x;

  if (tid < 4) qc[tid] = 0u;

  // U fragments resident in VGPRs for all 512 steps.
  bf16x8 Bf[2][8];
#pragma unroll
  for (int nt = 0; nt < 2; ++nt)
#pragma unroll
    for (int ks = 0; ks < 8; ++ks) {
      int n = w * 64 + ng * 32 + nt * 16 + lr;
      int k = kq * 256 + ks * 32 + lq * 8;
      Bf[nt][ks] = *(const bf16x8*)&Ut[(size_t)n * 1024 + k];
    }

  // elementwise ownership: batch b = lane, q = wave -> jl = 2q, 2q+1
  const int q = wave, b = lane;
  float bia[2][4];
#pragma unroll
  for (int p = 0; p < 2; ++p) {
    int hc = w * 16 + q * 2 + p;
    bia[p][0] = bi[hc]; bia[p][1] = bf_[hc]; bia[p][2] = bo[hc]; bia[p][3] = bg[hc];
  }
  float cst0 = 0.f, cst1 = 0.f;

  __syncthreads();  // qc init visible

  for (int t = 0; t < T_; ++t) {
    const u16* hin = hbuf + (size_t)(t & 1) * 65536;
    const int ep = (t >> 1) & 1;        // expected epoch parity of h_t

    // xg slice loads (latency hides under the h poll)
    const u16* xgp = xg + (size_t)t * 262144 + w * 4096;
    u32 xv[4];
#pragma unroll
    for (int g = 0; g < 4; ++g)
      xv[g] = *(const u32*)&xgp[b * 64 + g * 16 + q * 2];

    // ---- poll-stage OWN quarter kq (32 KB) into LDS; bit14 is the flag ----
    // pair thread handles rows R = kq*2048 + pairtid + 128*i, i=0..15
    // (row stride 2048 B; 4 bases x {-4096,-2048,0,+2048} imm offsets)
    {
      const u16* A = hin + (size_t)(kq * 2048 + pairtid) * 8;
      const u16* b0 = A + 2 * 1024;
      const u16* b1 = A + 6 * 1024;
      const u16* b2 = A + 10 * 1024;
      const u16* b3 = A + 14 * 1024;
      u32x4 v[16];
      u32 pend = 0xFFFFu;
      u32 spin = 0;
      do {
        if (spin > 1) __builtin_amdgcn_s_sleep(1);  // backoff after 2 fast rounds
        if (++spin > 65536u) break;                 // unreachable; anti-wedge only
        poll16(b0, b1, b2, b3, v);                  // fused: loads + vmcnt(0)
        __builtin_amdgcn_sched_barrier(0);
        if (ep) {
#pragma unroll
          for (int i = 0; i < 16; ++i)
            if (pend & (1u << i)) {
              u32 aa = v[i][0] & v[i][1] & v[i][2] & v[i][3];
              if ((aa & EPOCH_MASK) == EPOCH_MASK) {
                u32x4 wv;
                wv[0] = v[i][0] & EPOCH_CLR; wv[1] = v[i][1] & EPOCH_CLR;
                wv[2] = v[i][2] & EPOCH_CLR; wv[3] = v[i][3] & EPOCH_CLR;
                *(u32x4*)&hL[(size_t)(kq * 2048 + pairtid + (i << 7)) * 8] = wv;
                pend &= ~(1u << i);
              }
            }
        } else {
#pragma unroll
          for (int i = 0; i < 16; ++i)
            if (pend & (1u << i)) {
              u32 oo = v[i][0] | v[i][1] | v[i][2] | v[i][3];
              if ((oo & EPOCH_MASK) == 0u) {
                *(u32x4*)&hL[(size_t)(kq * 2048 + pairtid + (i << 7)) * 8] = v[i];
                pend &= ~(1u << i);
              }
            }
        }
      } while (pend);
    }
    // signal quarter share done; wait for partner wave (pair barrier)
    asm volatile("s_waitcnt lgkmcnt(0)" ::: "memory");
    if (lane == 0) atomicAdd(&qc[kq], 1u);
    {
      volatile u32* qp = (volatile u32*)&qc[kq];
      u32 tgt = 2u * (u32)(t + 1);
      u32 guard = 0;
      while (*qp < tgt) { if (++guard > (1u << 22)) break; }  // anti-wedge only
    }
    __builtin_amdgcn_sched_barrier(0);
    asm volatile("" ::: "memory");

    // ---- MFMA on own quarter (starts as soon as THIS quarter is staged) ----
    f32x4 acc[4][2];
#pragma unroll
    for (int mt = 0; mt < 4; ++mt) { acc[mt][0] = {0.f,0.f,0.f,0.f}; acc[mt][1] = {0.f,0.f,0.f,0.f}; }

#pragma unroll
    for (int ks = 0; ks < 8; ++ks) {
      int Gk = kq * 32 + ks * 4 + lq;
      bf16x8 af[4];
#pragma unroll
      for (int mt = 0; mt < 4; ++mt)
        af[mt] = *(const bf16x8*)&hL[(Gk * 64 + mt * 16 + lr) * 8];
#pragma unroll
      for (int mt = 0; mt < 4; ++mt) {
        acc[mt][0] = __builtin_amdgcn_mfma_f32_16x16x32_bf16(af[mt], Bf[0][ks], acc[mt][0], 0, 0, 0);
        acc[mt][1] = __builtin_amdgcn_mfma_f32_16x16x32_bf16(af[mt], Bf[1][ks], acc[mt][1], 0, 0, 0);
      }
    }
    __syncthreads();  // B2: all hL reads done -> safe to alias P

    // K-split partials -> LDS (stride 34: write 2-way, read 2-way => free)
#pragma unroll
    for (int mt = 0; mt < 4; ++mt)
#pragma unroll
      for (int nt = 0; nt < 2; ++nt)
#pragma unroll
        for (int r = 0; r < 4; ++r) {
          int m = mt * 16 + lq * 4 + r;
          int cc = nt * 16 + lr;
          P[((ng * 4 + kq) * 64 + m) * 34 + cc] = acc[mt][nt][r];
        }
    __syncthreads();  // B3: P complete

    float hv[2];
#pragma unroll
    for (int p = 0; p < 2; ++p) {
      int jl = q * 2 + p;
      float pre[4];
#pragma unroll
      for (int g = 0; g < 4; ++g) {
        int cc = (g & 1) * 16 + jl;
        int base = (g >> 1) * 4 * 64;
        float s = P[(base + 0 * 64 + b) * 34 + cc] + P[(base + 1 * 64 + b) * 34 + cc] +
                  P[(base + 2 * 64 + b) * 34 + cc] + P[(base + 3 * 64 + b) * 34 + cc];
        u16 xh = (u16)(p == 0 ? (xv[g] & 0xFFFFu) : (xv[g] >> 16));
        pre[g] = s + bf2f(xh) + bia[p][g];
      }
      float iv = sigm(pre[0]);
      float fv = sigm(pre[1]);
      float ov = sigm(pre[2]);
      float gv = tanh_(pre[3]);
      float cn = fv * (p == 0 ? cst0 : cst1) + iv * gv;
      if (p == 0) cst0 = cn; else cst1 = cn;
      hv[p] = ov * tanh_(cn);
    }

    float2 f2v; f2v.x = hv[0]; f2v.y = hv[1];
    *(float2*)&out[((size_t)b * 512 + t) * 1024 + w * 16 + q * 2] = f2v;

    if (t < T_ - 1) {
      // transposed gather (conflict-free both sides), then 128 atomic-row
      // 16B sc1 stores from waves 0 and 2.
      u32 hpack = (u32)f2bf(hv[0]) | ((u32)f2bf(hv[1]) << 16);
      if (((t + 1) >> 1) & 1) hpack |= EPOCH_MASK;
      hXt[q * 64 + b] = hpack;
      __syncthreads();  // B4: P reads + hXt writes complete
      if ((wave == 0) | (wave == 2)) {
        int gg = wave >> 1;  // granule half: cols gg*8..gg*8+7
        u32x4 hv4;
        hv4[0] = hXt[(gg * 4 + 0) * 64 + lane];
        hv4[1] = hXt[(gg * 4 + 1) * 64 + lane];
        hv4[2] = hXt[(gg * 4 + 2) * 64 + lane];
        hv4[3] = hXt[(gg * 4 + 3) * 64 + lane];
        u16* dst = hbuf + (size_t)((t + 1) & 1) * 65536 +
                   (size_t)((2 * w + gg) * 64 + lane) * 8;
        st16_sc1(dst, hv4);
      }
    } else {
      *(float2*)&out[(size_t)BTH + b * 1024 + w * 16 + q * 2] = f2v;          // h_last
      float2 c2v; c2v.x = cst0; c2v.y = cst1;
      *(float2*)&out[(size_t)BTH + B_ * H_ + b * 1024 + w * 16 + q * 2] = c2v; // c_last
    }
  }
}

// ---------------------------------------------------------------- launch
extern "C" void kernel_launch(void* const* d_in, const int* in_sizes, int n_in,
                              void* d_out, int out_size, void* d_ws, size_t ws_size,
                              hipStream_t stream) {
  const float* x  = (const float*)d_in[0];
  const float* Wi = (const float*)d_in[1];
  const float* Wf = (const float*)d_in[2];
  const float* Wo = (const float*)d_in[3];
  const float* Wg = (const float*)d_in[4];
  const float* Ui = (const float*)d_in[5];
  const float* Uf = (const float*)d_in[6];
  const float* Uo = (const float*)d_in[7];
  const float* Ug = (const float*)d_in[8];
  const float* bi = (const float*)d_in[9];
  const float* bf = (const float*)d_in[10];
  const float* bo = (const float*)d_in[11];
  const float* bg = (const float*)d_in[12];
  float* out = (float*)d_out;

  char* ws = (char*)d_ws;
  u16* xb   = (u16*)(ws + OFF_XB);
  u16* Wt   = (u16*)(ws + OFF_WT);
  u16* Ut   = (u16*)(ws + OFF_UT);
  u16* xg   = (u16*)(ws + OFF_XG);
  u16* hbuf = (u16*)(ws + OFF_HB);
  u32* flg  = (u32*)(ws + OFF_FLG);

  k_init<<<64, 256, 0, stream>>>(hbuf, flg);
  k_cvt_x<<<32768, 256, 0, stream>>>((const float4*)x, (ushort4*)xb);
  k_cvt_w<<<2048, 256, 0, stream>>>(Wi, Wf, Wo, Wg, Ui, Uf, Uo, Ug, Wt, Ut);
  k_gemm<<<dim3(32, 256), 256, 0, stream>>>(xb, Wt, xg);
  k_lstm<<<NWG, 512, 0, stream>>>(Ut, xg, hbuf, bi, bf, bo, bg, out);
}

// Round 9
// 3835.786 us; speedup vs baseline: 1.1662x; 1.0131x over previous
//
#include <hip/hip_runtime.h>
#include <stdint.h>
#include <stddef.h>

// LSTM: B=64, T=512, I=H=1024. fp32 in/out, bf16 MFMA compute internally.
//
//   k_lstm v8 = v7 with the producer tail shortened: h rows are assembled
//   IN-WAVE via __shfl and stored directly from registers -- no LDS gather,
//   no barrier before the h store.
//   - EPOCH-IN-VALUE sync (bit14 parity in every bf16; |h|<1 so bit14 free).
//   - Wave pair kq polls+stages ONLY h-quarter kq; pair-sync via LDS counter.
//   - Poll is ONE fused asm block (16x global_load_dwordx4 sc1 + vmcnt(0),
//     "=&v" outputs): no in-flight-load window for the allocator (v6 fix).
//   - EW ownership remapped so each 16B h-row's 4 u32 live in ONE wave:
//     gg=wave&1, cp=lane>>4, b=(wave>>1)*16+(lane&15); cols gg*8+cp*2,+1.
//     Row (2w+gg, b) = lanes {m,m+16,m+32,m+48} -> 3 shfls -> dwordx4 sc1
//     issued ~30cyc after gate math (v7: ~400cyc gather+barrier+LDS-read).
//   - B4 stays as the pure P/hL alias fence (nothing behind it).
//   - Bounded spins: any protocol stall -> diagnosable failure, not a wedge.

typedef unsigned short u16;
typedef unsigned int u32;
typedef short bf16x8 __attribute__((ext_vector_type(8)));
typedef float f32x4 __attribute__((ext_vector_type(4)));
typedef u32 u32x4 __attribute__((ext_vector_type(4)));

#define B_ 64
#define T_ 512
#define I_ 1024
#define H_ 1024
#define NWG 64
#define BTH (B_ * T_ * H_)

// ws layout (bytes)
#define OFF_XB 0UL                 // 64 MB  : x bf16 [64][512][1024]
#define OFF_WT 67108864UL          // 8 MB   : Wcat bf16, reordered [4096][1024]
#define OFF_UT 75497472UL          // 8 MB   : Ucat bf16, reordered [4096][1024]
#define OFF_XG 83886080UL          // 256 MB : xg bf16 [512][64][64][64]
#define OFF_HB 352321536UL         // 256 KB : h dbuf, granule layout 2x[128][64][8]
#define OFF_FLG 352583680UL        // flags u32[64] (unused by k_lstm)

#define EPOCH_MASK 0x40004000u
#define EPOCH_CLR  0xBFFFBFFFu

// LDS map (k_lstm)
#define LDS_QC 131072   // u32[4] quarter counters
#define LDS_SZ 131088

__device__ __forceinline__ u16 f2bf(float f) {
  u32 u = __builtin_bit_cast(u32, f);
  return (u16)((u + 0x7FFFu + ((u >> 16) & 1u)) >> 16);
}
__device__ __forceinline__ float bf2f(u16 h) {
  u32 u = ((u32)h) << 16;
  return __builtin_bit_cast(float, u);
}
__device__ __forceinline__ float sigm(float x) { return 1.f / (1.f + __expf(-x)); }
__device__ __forceinline__ float tanh_(float x) {
  float e = __expf(-2.f * fabsf(x));
  float t = (1.f - e) / (1.f + e);
  return x >= 0.f ? t : -t;
}
__device__ __forceinline__ void async16(const void* g, void* l) {
  __builtin_amdgcn_global_load_lds((const __attribute__((address_space(1))) void*)g,
                                   (__attribute__((address_space(3))) void*)l, 16, 0, 0);
}
__device__ __forceinline__ void st16_sc1(u16* p, u32x4 v) {
  asm volatile("global_store_dwordx4 %0, %1, off sc1" : : "v"(p), "v"(v) : "memory");
}

// Fused poll round: load 16 rows (4 bases x 4 signed imm offsets, stride
// 2048 B) device-coherent, wait inside the SAME asm block. Outputs are fully
// defined at block end -- no in-flight-load window for the allocator to break.
__device__ __forceinline__ void poll16(const u16* b0, const u16* b1,
                                       const u16* b2, const u16* b3,
                                       u32x4 v[16]) {
  asm volatile(
      "global_load_dwordx4 %0, %16, off offset:-4096 sc1\n\t"
      "global_load_dwordx4 %1, %16, off offset:-2048 sc1\n\t"
      "global_load_dwordx4 %2, %16, off sc1\n\t"
      "global_load_dwordx4 %3, %16, off offset:2048 sc1\n\t"
      "global_load_dwordx4 %4, %17, off offset:-4096 sc1\n\t"
      "global_load_dwordx4 %5, %17, off offset:-2048 sc1\n\t"
      "global_load_dwordx4 %6, %17, off sc1\n\t"
      "global_load_dwordx4 %7, %17, off offset:2048 sc1\n\t"
      "global_load_dwordx4 %8, %18, off offset:-4096 sc1\n\t"
      "global_load_dwordx4 %9, %18, off offset:-2048 sc1\n\t"
      "global_load_dwordx4 %10, %18, off sc1\n\t"
      "global_load_dwordx4 %11, %18, off offset:2048 sc1\n\t"
      "global_load_dwordx4 %12, %19, off offset:-4096 sc1\n\t"
      "global_load_dwordx4 %13, %19, off offset:-2048 sc1\n\t"
      "global_load_dwordx4 %14, %19, off sc1\n\t"
      "global_load_dwordx4 %15, %19, off offset:2048 sc1\n\t"
      "s_waitcnt vmcnt(0)"
      : "=&v"(v[0]), "=&v"(v[1]), "=&v"(v[2]), "=&v"(v[3]),
        "=&v"(v[4]), "=&v"(v[5]), "=&v"(v[6]), "=&v"(v[7]),
        "=&v"(v[8]), "=&v"(v[9]), "=&v"(v[10]), "=&v"(v[11]),
        "=&v"(v[12]), "=&v"(v[13]), "=&v"(v[14]), "=&v"(v[15])
      : "v"(b0), "v"(b1), "v"(b2), "v"(b3)
      : "memory");
}

// ---------------------------------------------------------------- init
__global__ void k_init(u16* hbuf, u32* flg) {
  int i = blockIdx.x * 256 + threadIdx.x;  // 64 blocks -> 16384 threads
  uint4 z;
  if (i < 8192) {               // buf0 = h_0 = zeros, epoch 0
    z.x = 0u; z.y = 0u; z.z = 0u; z.w = 0u;
  } else {                      // buf1 = poison with bit14=1 (!= h_1's epoch 0)
    z.x = EPOCH_MASK; z.y = EPOCH_MASK; z.z = EPOCH_MASK; z.w = EPOCH_MASK;
  }
  ((uint4*)hbuf)[i] = z;
  if (i < NWG) flg[i] = 0u;
}

// ---------------------------------------------------------------- x -> bf16
__global__ void k_cvt_x(const float4* __restrict__ x, ushort4* __restrict__ xb) {
  size_t i = (size_t)blockIdx.x * 256 + threadIdx.x;  // 8388608 float4s
  float4 v = x[i];
  ushort4 o;
  o.x = f2bf(v.x); o.y = f2bf(v.y); o.z = f2bf(v.z); o.w = f2bf(v.w);
  xb[i] = o;
}

// ---------------------------------------------------------------- W/U -> bf16, reordered
__global__ void k_cvt_w(const float* __restrict__ Wi, const float* __restrict__ Wf,
                        const float* __restrict__ Wo, const float* __restrict__ Wg,
                        const float* __restrict__ Ui, const float* __restrict__ Uf,
                        const float* __restrict__ Uo, const float* __restrict__ Ug,
                        u16* __restrict__ Wt, u16* __restrict__ Ut) {
  int idx = blockIdx.x * 256 + threadIdx.x;  // 4096 rows * 128 segs
  int r = idx >> 7;
  int s = idx & 127;
  int w = r >> 6, c = r & 63, g = c >> 4, jl = c & 15;
  int hrow = w * 16 + jl;
  const float* Wsrc = (g == 0) ? Wi : (g == 1) ? Wf : (g == 2) ? Wo : Wg;
  const float* Usrc = (g == 0) ? Ui : (g == 1) ? Uf : (g == 2) ? Uo : Ug;
  int so = hrow * 1024 + s * 8;
  int dovr = r * 1024 + s * 8;
  ushort4 a, b;
  a.x = f2bf(Wsrc[so + 0]); a.y = f2bf(Wsrc[so + 1]); a.z = f2bf(Wsrc[so + 2]); a.w = f2bf(Wsrc[so + 3]);
  b.x = f2bf(Wsrc[so + 4]); b.y = f2bf(Wsrc[so + 5]); b.z = f2bf(Wsrc[so + 6]); b.w = f2bf(Wsrc[so + 7]);
  *(ushort4*)&Wt[dovr] = a;
  *(ushort4*)&Wt[dovr + 4] = b;
  a.x = f2bf(Usrc[so + 0]); a.y = f2bf(Usrc[so + 1]); a.z = f2bf(Usrc[so + 2]); a.w = f2bf(Usrc[so + 3]);
  b.x = f2bf(Usrc[so + 4]); b.y = f2bf(Usrc[so + 5]); b.z = f2bf(Usrc[so + 6]); b.w = f2bf(Usrc[so + 7]);
  *(ushort4*)&Ut[dovr] = a;
  *(ushort4*)&Ut[dovr + 4] = b;
}

// ---------------------------------------------------------------- input GEMM
__global__ __launch_bounds__(256) void k_gemm(const u16* __restrict__ xb,
                                              const u16* __restrict__ Wt,
                                              u16* __restrict__ xg) {
  __shared__ u16 As[4 * 128 * 8];
  __shared__ u16 Bs[4 * 128 * 8];
  const int tid = threadIdx.x;
  const int lane = tid & 63, wave = tid >> 6;
  const int wm = wave >> 1, wn = wave & 1;
  const int lr = lane & 15, lq = lane >> 4;
  const int m0 = blockIdx.y * 128, n0 = blockIdx.x * 128;

  f32x4 acc[4][4];
#pragma unroll
  for (int mt = 0; mt < 4; ++mt)
#pragma unroll
    for (int nt = 0; nt < 4; ++nt) acc[mt][nt] = {0.f, 0.f, 0.f, 0.f};

  for (int kk = 0; kk < 32; ++kk) {
    int k0 = kk * 32;
    __syncthreads();
#pragma unroll
    for (int uu = 0; uu < 2; ++uu) {
      int u = wave * 2 + uu;
      int kq = u >> 1, rh = u & 1;
      int row = rh * 64 + lane;
      async16(&xb[(size_t)(m0 + row) * 1024 + k0 + kq * 8], &As[kq * 1024 + rh * 512]);
      async16(&Wt[(size_t)(n0 + row) * 1024 + k0 + kq * 8], &Bs[kq * 1024 + rh * 512]);
    }
    __syncthreads();

    bf16x8 af[4], bfr[4];
#pragma unroll
    for (int mt = 0; mt < 4; ++mt)
      af[mt] = *(const bf16x8*)&As[lq * 1024 + (wm * 64 + mt * 16 + lr) * 8];
#pragma unroll
    for (int nt = 0; nt < 4; ++nt)
      bfr[nt] = *(const bf16x8*)&Bs[lq * 1024 + (wn * 64 + nt * 16 + lr) * 8];
#pragma unroll
    for (int mt = 0; mt < 4; ++mt)
#pragma unroll
      for (int nt = 0; nt < 4; ++nt)
        acc[mt][nt] = __builtin_amdgcn_mfma_f32_16x16x32_bf16(af[mt], bfr[nt], acc[mt][nt], 0, 0, 0);
  }

#pragma unroll
  for (int mt = 0; mt < 4; ++mt)
#pragma unroll
    for (int nt = 0; nt < 4; ++nt)
#pragma unroll
      for (int r = 0; r < 4; ++r) {
        int mg = m0 + wm * 64 + mt * 16 + lq * 4 + r;
        int ngl = n0 + wn * 64 + nt * 16 + lr;
        int b = mg >> 9, t = mg & 511;
        int w = ngl >> 6, c = ngl & 63;
        xg[(size_t)t * 262144 + w * 4096 + b * 64 + c] = f2bf(acc[mt][nt][r]);
      }
}

// ---------------------------------------------------------------- recurrence
// 64 WGs x 512 threads (8 waves = 4 kq x 2 ng). WG w owns gate cols
// [64w, 64w+64) => h cols [16w, 16w+16). Pair kq stages h-quarter kq only.
__global__ __launch_bounds__(512, 2) void k_lstm(
    const u16* __restrict__ Ut, const u16* __restrict__ xg, u16* hbuf,
    const float* __restrict__ bi, const float* __restrict__ bf_,
    const float* __restrict__ bo, const float* __restrict__ bg,
    float* __restrict__ out) {
  __shared__ __align__(16) unsigned char LDSB[LDS_SZ];
  u16* hL = (u16*)LDSB;                 // h staged: [granule 128][b 64][8 u16]
  float* P = (float*)LDSB;              // aliased after B2: [ng 2][kq 4][b 64][34]
  u32* qc = (u32*)(LDSB + LDS_QC);      // quarter ready counters (monotone)

  const int tid = threadIdx.x;
  const int lane = tid & 63, wave = tid >> 6;
  const int lr = lane & 15, lq = lane >> 4;
  const int kq = wave >> 1, ng = wave & 1;
  const int pairtid = ng * 64 + lane;   // 0..127 within pair kq
  const int w = blockIdx.x;

  if (tid < 4) qc[tid] = 0u;

  // U fragments resident in VGPRs for all 512 steps.
  bf16x8 Bf[2][8];
#pragma unroll
  for (int nt = 0; nt < 2; ++nt)
#pragma unroll
    for (int ks = 0; ks < 8; ++ks) {
      int n = w * 64 + ng * 32 + nt * 16 + lr;
      int k = kq * 256 + ks * 32 + lq * 8;
      Bf[nt][ks] = *(const bf16x8*)&Ut[(size_t)n * 1024 + k];
    }

  // elementwise ownership (row-direct): gg = wave&1, cp = lane>>4,
  // b = (wave>>1)*16 + (lane&15); this thread owns h cols c0, c0+1 of batch b
  // where c0 = gg*8 + cp*2. Row (2w+gg, b)'s 4 u32 = lanes {m,m+16,m+32,m+48}
  // of ONE wave -> shfl-gather -> atomic 16B row store, no LDS, no barrier.
  const int gg = wave & 1, cp = lane >> 4;
  const int b = ((wave >> 1) << 4) + (lane & 15);
  const int c0 = gg * 8 + cp * 2;
  float bia[2][4];
#pragma unroll
  for (int p = 0; p < 2; ++p) {
    int hc = w * 16 + c0 + p;
    bia[p][0] = bi[hc]; bia[p][1] = bf_[hc]; bia[p][2] = bo[hc]; bia[p][3] = bg[hc];
  }
  float cst0 = 0.f, cst1 = 0.f;

  __syncthreads();  // qc init visible

  for (int t = 0; t < T_; ++t) {
    const u16* hin = hbuf + (size_t)(t & 1) * 65536;
    const int ep = (t >> 1) & 1;        // expected epoch parity of h_t

    // xg slice loads (latency hides under the h poll)
    const u16* xgp = xg + (size_t)t * 262144 + w * 4096;
    u32 xv[4];
#pragma unroll
    for (int g = 0; g < 4; ++g)
      xv[g] = *(const u32*)&xgp[b * 64 + g * 16 + c0];

    // ---- poll-stage OWN quarter kq (32 KB) into LDS; bit14 is the flag ----
    // pair thread handles rows R = kq*2048 + pairtid + 128*i, i=0..15
    // (row stride 2048 B; 4 bases x {-4096,-2048,0,+2048} imm offsets)
    {
      const u16* A = hin + (size_t)(kq * 2048 + pairtid) * 8;
      const u16* b0 = A + 2 * 1024;
      const u16* b1 = A + 6 * 1024;
      const u16* b2 = A + 10 * 1024;
      const u16* b3 = A + 14 * 1024;
      u32x4 v[16];
      u32 pend = 0xFFFFu;
      u32 spin = 0;
      do {
        if (spin > 1) __builtin_amdgcn_s_sleep(1);  // backoff after 2 fast rounds
        if (++spin > 65536u) break;                 // unreachable; anti-wedge only
        poll16(b0, b1, b2, b3, v);                  // fused: loads + vmcnt(0)
        __builtin_amdgcn_sched_barrier(0);
        if (ep) {
#pragma unroll
          for (int i = 0; i < 16; ++i)
            if (pend & (1u << i)) {
              u32 aa = v[i][0] & v[i][1] & v[i][2] & v[i][3];
              if ((aa & EPOCH_MASK) == EPOCH_MASK) {
                u32x4 wv;
                wv[0] = v[i][0] & EPOCH_CLR; wv[1] = v[i][1] & EPOCH_CLR;
                wv[2] = v[i][2] & EPOCH_CLR; wv[3] = v[i][3] & EPOCH_CLR;
                *(u32x4*)&hL[(size_t)(kq * 2048 + pairtid + (i << 7)) * 8] = wv;
                pend &= ~(1u << i);
              }
            }
        } else {
#pragma unroll
          for (int i = 0; i < 16; ++i)
            if (pend & (1u << i)) {
              u32 oo = v[i][0] | v[i][1] | v[i][2] | v[i][3];
              if ((oo & EPOCH_MASK) == 0u) {
                *(u32x4*)&hL[(size_t)(kq * 2048 + pairtid + (i << 7)) * 8] = v[i];
                pend &= ~(1u << i);
              }
            }
        }
      } while (pend);
    }
    // signal quarter share done; wait for partner wave (pair barrier)
    asm volatile("s_waitcnt lgkmcnt(0)" ::: "memory");
    if (lane == 0) atomicAdd(&qc[kq], 1u);
    {
      volatile u32* qp = (volatile u32*)&qc[kq];
      u32 tgt = 2u * (u32)(t + 1);
      u32 guard = 0;
      while (*qp < tgt) { if (++guard > (1u << 22)) break; }  // anti-wedge only
    }
    __builtin_amdgcn_sched_barrier(0);
    asm volatile("" ::: "memory");

    // ---- MFMA on own quarter (starts as soon as THIS quarter is staged) ----
    f32x4 acc[4][2];
#pragma unroll
    for (int mt = 0; mt < 4; ++mt) { acc[mt][0] = {0.f,0.f,0.f,0.f}; acc[mt][1] = {0.f,0.f,0.f,0.f}; }

#pragma unroll
    for (int ks = 0; ks < 8; ++ks) {
      int Gk = kq * 32 + ks * 4 + lq;
      bf16x8 af[4];
#pragma unroll
      for (int mt = 0; mt < 4; ++mt)
        af[mt] = *(const bf16x8*)&hL[(Gk * 64 + mt * 16 + lr) * 8];
#pragma unroll
      for (int mt = 0; mt < 4; ++mt) {
        acc[mt][0] = __builtin_amdgcn_mfma_f32_16x16x32_bf16(af[mt], Bf[0][ks], acc[mt][0], 0, 0, 0);
        acc[mt][1] = __builtin_amdgcn_mfma_f32_16x16x32_bf16(af[mt], Bf[1][ks], acc[mt][1], 0, 0, 0);
      }
    }
    __syncthreads();  // B2: all hL reads done -> safe to alias P

    // K-split partials -> LDS (stride 34: write 2-way => free)
#pragma unroll
    for (int mt = 0; mt < 4; ++mt)
#pragma unroll
      for (int nt = 0; nt < 2; ++nt)
#pragma unroll
        for (int r = 0; r < 4; ++r) {
          int m = mt * 16 + lq * 4 + r;
          int cc = nt * 16 + lr;
          P[((ng * 4 + kq) * 64 + m) * 34 + cc] = acc[mt][nt][r];
        }
    __syncthreads();  // B3: P complete

    float hv[2];
#pragma unroll
    for (int p = 0; p < 2; ++p) {
      int jl = c0 + p;
      float pre[4];
#pragma unroll
      for (int g = 0; g < 4; ++g) {
        int cc = (g & 1) * 16 + jl;
        int base = (g >> 1) * 4 * 64;
        float s = P[(base + 0 * 64 + b) * 34 + cc] + P[(base + 1 * 64 + b) * 34 + cc] +
                  P[(base + 2 * 64 + b) * 34 + cc] + P[(base + 3 * 64 + b) * 34 + cc];
        u16 xh = (u16)(p == 0 ? (xv[g] & 0xFFFFu) : (xv[g] >> 16));
        pre[g] = s + bf2f(xh) + bia[p][g];
      }
      float iv = sigm(pre[0]);
      float fv = sigm(pre[1]);
      float ov = sigm(pre[2]);
      float gv = tanh_(pre[3]);
      float cn = fv * (p == 0 ? cst0 : cst1) + iv * gv;
      if (p == 0) cst0 = cn; else cst1 = cn;
      hv[p] = ov * tanh_(cn);
    }

    float2 f2v; f2v.x = hv[0]; f2v.y = hv[1];

    if (t < T_ - 1) {
      // h broadcast FIRST (critical path): in-wave shfl gather of the 4 u32
      // of row (2w+gg, b), then atomic 16B sc1 store from lanes 0..15.
      u32 hpack = (u32)f2bf(hv[0]) | ((u32)f2bf(hv[1]) << 16);
      if (((t + 1) >> 1) & 1) hpack |= EPOCH_MASK;
      int ml = lane & 15;
      u32x4 hv4;
      hv4[0] = (u32)__shfl((int)hpack, ml);
      hv4[1] = (u32)__shfl((int)hpack, ml + 16);
      hv4[2] = (u32)__shfl((int)hpack, ml + 32);
      hv4[3] = (u32)__shfl((int)hpack, ml + 48);
      if (lane < 16) {
        u16* dst = hbuf + (size_t)((t + 1) & 1) * 65536 +
                   (size_t)((2 * w + gg) * 64 + b) * 8;
        st16_sc1(dst, hv4);
      }
      // out store (off critical path)
      *(float2*)&out[((size_t)b * 512 + t) * 1024 + w * 16 + c0] = f2v;
    } else {
      *(float2*)&out[((size_t)b * 512 + t) * 1024 + w * 16 + c0] = f2v;
      *(float2*)&out[(size_t)BTH + b * 1024 + w * 16 + c0] = f2v;             // h_last
      float2 c2v; c2v.x = cst0; c2v.y = cst1;
      *(float2*)&out[(size_t)BTH + B_ * H_ + b * 1024 + w * 16 + c0] = c2v;   // c_last
    }

    __syncthreads();  // B4: P reads done before next step's poll ds_writes
  }
}

// ---------------------------------------------------------------- launch
extern "C" void kernel_launch(void* const* d_in, const int* in_sizes, int n_in,
                              void* d_out, int out_size, void* d_ws, size_t ws_size,
                              hipStream_t stream) {
  const float* x  = (const float*)d_in[0];
  const float* Wi = (const float*)d_in[1];
  const float* Wf = (const float*)d_in[2];
  const float* Wo = (const float*)d_in[3];
  const float* Wg = (const float*)d_in[4];
  const float* Ui = (const float*)d_in[5];
  const float* Uf = (const float*)d_in[6];
  const float* Uo = (const float*)d_in[7];
  const float* Ug = (const float*)d_in[8];
  const float* bi = (const float*)d_in[9];
  const float* bf = (const float*)d_in[10];
  const float* bo = (const float*)d_in[11];
  const float* bg = (const float*)d_in[12];
  float* out = (float*)d_out;

  char* ws = (char*)d_ws;
  u16* xb   = (u16*)(ws + OFF_XB);
  u16* Wt   = (u16*)(ws + OFF_WT);
  u16* Ut   = (u16*)(ws + OFF_UT);
  u16* xg   = (u16*)(ws + OFF_XG);
  u16* hbuf = (u16*)(ws + OFF_HB);
  u32* flg  = (u32*)(ws + OFF_FLG);

  k_init<<<64, 256, 0, stream>>>(hbuf, flg);
  k_cvt_x<<<32768, 256, 0, stream>>>((const float4*)x, (ushort4*)xb);
  k_cvt_w<<<2048, 256, 0, stream>>>(Wi, Wf, Wo, Wg, Ui, Uf, Uo, Ug, Wt, Ut);
  k_gemm<<<dim3(32, 256), 256, 0, stream>>>(xb, Wt, xg);
  k_lstm<<<NWG, 512, 0, stream>>>(Ut, xg, hbuf, bi, bf, bo, bg, out);
}